// Round 19
// baseline (357.040 us; speedup 1.0000x reference)
//
#include <hip/hip_runtime.h>
#include <math.h>

typedef __attribute__((ext_vector_type(8))) short bf16x8;
typedef __attribute__((ext_vector_type(4))) float f32x4;
typedef __attribute__((ext_vector_type(2))) _Float16 h2;

#define BSHIFT 7               // 128 nodes per bucket
#define CH 8192                // edges per block in bucket hist/scatter

__device__ inline unsigned short f32_to_bf16_bits(float f) {
    unsigned int u = __float_as_uint(f);
    unsigned int r = (u + 0x7fffu + ((u >> 16) & 1u)) >> 16;   // RNE
    return (unsigned short)r;
}
__device__ inline float bf16_bits_to_f32(unsigned short h) {
    return __uint_as_float(((unsigned int)h) << 16);
}
__device__ inline h2 u2h(unsigned u) { return __builtin_bit_cast(h2, u); }
__device__ inline unsigned h2u(h2 h) { return __builtin_bit_cast(unsigned, h); }

// single-instruction lane xor-swizzle add (BitMode: (xor<<10)|0x1F)
#define SWZ_ADD(t, imm) \
    t += __int_as_float(__builtin_amdgcn_ds_swizzle(__float_as_int(t), imm))

// fp16 pair dot with f32 accumulate (v_dot2_f32_f16)
__device__ inline float dot2acc(h2 a, h2 b, float c) {
#if defined(__has_builtin)
#if __has_builtin(__builtin_amdgcn_fdot2)
    return __builtin_amdgcn_fdot2(a, b, c, false);
#else
    return c + (float)a[0] * (float)b[0] + (float)a[1] * (float)b[1];
#endif
#else
    return c + (float)a[0] * (float)b[0] + (float)a[1] * (float)b[1];
#endif
}

// ================= exact per-block-count CSR build =================
// bh[block][bucket] matrix: hist writes per-block LDS histograms (no global
// atomics); scan turns them into exact per-(block,bucket) bases in place;
// scatter loads its block's cursors and scatters with LDS atomics only.

__global__ __launch_bounds__(256) void bucket_hist(
    const int* __restrict__ dst, int* __restrict__ bh, int E, int nb, int nbp)
{
    __shared__ int h[1024];
    for (int i = threadIdx.x; i < nb; i += 256) h[i] = 0;
    __syncthreads();
    int e0 = blockIdx.x * CH, e1 = min(e0 + CH, E);
    for (int e = e0 + (int)threadIdx.x; e < e1; e += 256)
        atomicAdd(&h[dst[e] >> BSHIFT], 1);
    __syncthreads();
    for (int b = threadIdx.x; b < nb; b += 256)
        bh[(size_t)blockIdx.x * nbp + b] = h[b];
}

// one block, 1024 threads: thread t = bucket t. Per-bucket serial prefix
// over blocks (coalesced across threads), LDS scan across buckets, add base.
__global__ void bucket_scan(int* __restrict__ bh, int* __restrict__ bbase,
                            int* __restrict__ rowstart,
                            int nb, int nbp, int kgrid, int E, int N)
{
    __shared__ int sh[1024];
    int t = threadIdx.x;
    int run = 0;
    if (t < nb) {
        for (int b = 0; b < kgrid; ++b) {
            int* p = &bh[(size_t)b * nbp + t];
            int v = *p;
            *p = run;          // exclusive within bucket
            run += v;
        }
    }
    sh[t] = run;               // bucket total
    __syncthreads();
    for (int d = 1; d < 1024; d <<= 1) {
        int a = (t >= d) ? sh[t - d] : 0;
        __syncthreads();
        sh[t] += a;
        __syncthreads();
    }
    int base = sh[t] - run;    // exclusive bucket base
    if (t < nb) {
        bbase[t] = base;
        for (int b = 0; b < kgrid; ++b) bh[(size_t)b * nbp + t] += base;
    }
    if (t == nb) bbase[t] = E;
    if (t == 0) rowstart[N] = E;
}

__global__ __launch_bounds__(256) void bucket_scatter(
    const int* __restrict__ src, const int* __restrict__ dst,
    const int* __restrict__ bh, unsigned* __restrict__ pairs, int E, int nb, int nbp)
{
    __shared__ int cur[1024];
    for (int i = threadIdx.x; i < nb; i += 256)
        cur[i] = bh[(size_t)blockIdx.x * nbp + i];
    __syncthreads();
    int e0 = blockIdx.x * CH, e1 = min(e0 + CH, E);
    for (int e = e0 + (int)threadIdx.x; e < e1; e += 256) {
        int d = dst[e];
        int pos = atomicAdd(&cur[d >> BSHIFT], 1);
        pairs[pos] = ((unsigned)src[e] << BSHIFT) | (unsigned)(d & 127);
    }
}

// one block per bucket: local hist + scan -> rowstart, then local scatter.
__global__ __launch_bounds__(256) void bucket_finalize(
    const unsigned* __restrict__ pairs, const int* __restrict__ bbase,
    int* __restrict__ rowstart, int* __restrict__ csr_src, int N)
{
    __shared__ int h[128];
    __shared__ int sh[256];
    int b = blockIdx.x;
    int p0 = bbase[b], p1 = bbase[b + 1];
    int t = threadIdx.x;
    if (t < 128) h[t] = 0;
    __syncthreads();
    for (int e = p0 + t; e < p1; e += 256)
        atomicAdd(&h[pairs[e] & 127], 1);
    __syncthreads();
    int v = (t < 128) ? h[t] : 0;
    sh[t] = v;
    __syncthreads();
    for (int d = 1; d < 256; d <<= 1) {
        int a = (t >= d) ? sh[t - d] : 0;
        __syncthreads();
        sh[t] += a;
        __syncthreads();
    }
    if (t < 128) {
        int off = sh[t] - v;
        int node = (b << BSHIFT) + t;
        if (node < N) rowstart[node] = p0 + off;
        h[t] = p0 + off;
    }
    __syncthreads();
    for (int e = p0 + t; e < p1; e += 256) {
        unsigned pr = pairs[e];
        int pos = atomicAdd(&h[pr & 127], 1);
        csr_src[pos] = (int)(pr >> BSHIFT);
    }
}

// ================= weight prepack (all layers, one launch) =================

__device__ inline void prepack_one(const float* __restrict__ W, unsigned short* __restrict__ P,
                                   int FIN, int FOUT, int ii) {
    int NT = FOUT >> 4, NK = FIN >> 5;
    int part = NT * NK * 512;
    int j = ii & 7;
    int lane = (ii >> 3) & 63;
    int rest = ii >> 9;
    int ks = rest % NK;
    int t = rest / NK;
    int k = ks * 32 + (lane >> 4) * 8 + j;
    int c = t * 16 + (lane & 15);
    float w = W[(size_t)k * FOUT + c];
    unsigned short hi = f32_to_bf16_bits(w);
    unsigned short lo = f32_to_bf16_bits(w - bf16_bits_to_f32(hi));
    P[ii] = hi;
    P[part + ii] = lo;
}

__global__ void prepack_all(
    const float* Wl1, const float* Wr1, const float* Wl2, const float* Wr2,
    const float* Wl3, const float* Wr3, const float* Wl4, const float* Wr4,
    unsigned short* pWl1, unsigned short* pWr1, unsigned short* pWl2, unsigned short* pWr2,
    unsigned short* pWl3, unsigned short* pWr3, unsigned short* pWl4, unsigned short* pWr4)
{
    int i = blockIdx.x * 256 + threadIdx.x;
    if      (i < 8192)  prepack_one(Wl1, pWl1, 128, 64, i);
    else if (i < 16384) prepack_one(Wr1, pWr1, 128, 64, i - 8192);
    else if (i < 20480) prepack_one(Wl2, pWl2, 64, 64, i - 16384);
    else if (i < 24576) prepack_one(Wr2, pWr2, 64, 64, i - 20480);
    else if (i < 28672) prepack_one(Wl3, pWl3, 64, 64, i - 24576);
    else if (i < 32768) prepack_one(Wr3, pWr3, 64, 64, i - 28672);
    else if (i < 34816) prepack_one(Wl4, pWl4, 64, 32, i - 32768);
    else if (i < 36864) prepack_one(Wr4, pWr4, 64, 32, i - 34816);
}

// ================= MFMA projection + att-dot epilogue =================
// IN16: input h stored fp16 (layers 2-4); fp16 = bf16hi + bf16lo exactly.

template<int FIN, int FOUT, bool IN16>
__global__ __launch_bounds__(256) void proj_mfma_kernel(
    const void* __restrict__ xin,
    const unsigned short* __restrict__ pWl, const unsigned short* __restrict__ pWr,
    const float* __restrict__ att,
    _Float16* __restrict__ xlh, _Float16* __restrict__ xrh,
    float* __restrict__ dl, float* __restrict__ dr, int n)
{
    constexpr int NT = FOUT >> 4;
    constexpr int NK = FIN >> 5;
    constexpr int PART = NT * NK * 512;
    const int wave = threadIdx.x >> 6;
    const int lane = threadIdx.x & 63;
    const int row0 = blockIdx.x * 64 + wave * 16;
    int arow = row0 + (lane & 15);
    if (arow >= n) arow = n - 1;
    const int khalf = lane >> 4;

    f32x4 accl[NT], accr[NT];
#pragma unroll
    for (int t = 0; t < NT; ++t) {
        accl[t] = (f32x4){0.f, 0.f, 0.f, 0.f};
        accr[t] = (f32x4){0.f, 0.f, 0.f, 0.f};
    }

#pragma unroll
    for (int ks = 0; ks < NK; ++ks) {
        float av[8];
        if (IN16) {
            const _Float16* xrow = (const _Float16*)xin + (size_t)arow * FIN + khalf * 8;
            float4 raw = *(const float4*)(xrow + ks * 32);
            const unsigned* u = (const unsigned*)&raw;
#pragma unroll
            for (int j = 0; j < 4; ++j) {
                h2 p = u2h(u[j]);
                av[2 * j]     = (float)p[0];
                av[2 * j + 1] = (float)p[1];
            }
        } else {
            const float* xrow = (const float*)xin + (size_t)arow * FIN + khalf * 8;
            float4 a0 = *(const float4*)(xrow + ks * 32);
            float4 a1 = *(const float4*)(xrow + ks * 32 + 4);
            av[0] = a0.x; av[1] = a0.y; av[2] = a0.z; av[3] = a0.w;
            av[4] = a1.x; av[5] = a1.y; av[6] = a1.z; av[7] = a1.w;
        }
        bf16x8 ah, al;
#pragma unroll
        for (int j = 0; j < 8; ++j) {
            unsigned short h = f32_to_bf16_bits(av[j]);
            ah[j] = (short)h;
            al[j] = (short)f32_to_bf16_bits(av[j] - bf16_bits_to_f32(h));
        }
#pragma unroll
        for (int t = 0; t < NT; ++t) {
            const unsigned short* bpl = pWl + ((size_t)(t * NK + ks) * 64 + lane) * 8;
            bf16x8 bh  = *(const bf16x8*)bpl;
            bf16x8 blo = *(const bf16x8*)(bpl + PART);
            accl[t] = __builtin_amdgcn_mfma_f32_16x16x32_bf16(ah, bh,  accl[t], 0, 0, 0);
            accl[t] = __builtin_amdgcn_mfma_f32_16x16x32_bf16(ah, blo, accl[t], 0, 0, 0);
            accl[t] = __builtin_amdgcn_mfma_f32_16x16x32_bf16(al, bh,  accl[t], 0, 0, 0);
            const unsigned short* bpr = pWr + ((size_t)(t * NK + ks) * 64 + lane) * 8;
            bh  = *(const bf16x8*)bpr;
            blo = *(const bf16x8*)(bpr + PART);
            accr[t] = __builtin_amdgcn_mfma_f32_16x16x32_bf16(ah, bh,  accr[t], 0, 0, 0);
            accr[t] = __builtin_amdgcn_mfma_f32_16x16x32_bf16(ah, blo, accr[t], 0, 0, 0);
            accr[t] = __builtin_amdgcn_mfma_f32_16x16x32_bf16(al, bh,  accr[t], 0, 0, 0);
        }
    }

    const int orow0 = row0 + khalf * 4;
    const int colb = lane & 15;
    float attc[NT];
#pragma unroll
    for (int t = 0; t < NT; ++t) attc[t] = att[t * 16 + colb];

#pragma unroll
    for (int t = 0; t < NT; ++t) {
        int col = t * 16 + colb;
#pragma unroll
        for (int r = 0; r < 4; ++r) {
            int rr = orow0 + r;
            if (rr < n) {
                xlh[(size_t)rr * FOUT + col] = (_Float16)accl[t][r];
                xrh[(size_t)rr * FOUT + col] = (_Float16)accr[t][r];
            }
        }
    }
#pragma unroll
    for (int r = 0; r < 4; ++r) {
        float pl = 0.f, pr = 0.f;
#pragma unroll
        for (int t = 0; t < NT; ++t) { pl += accl[t][r] * attc[t]; pr += accr[t][r] * attc[t]; }
#pragma unroll
        for (int off = 1; off < 16; off <<= 1) {
            pl += __shfl_xor(pl, off);
            pr += __shfl_xor(pr, off);
        }
        int rr = orow0 + r;
        if (colb == 0 && rr < n) { dl[rr] = pl; dr[rr] = pr; }
    }
}

// ================= per-dst online-softmax aggregation =================
// Static persistent grid-stride (2048 blocks = 32 waves/CU); group-per-node,
// 8 feats/lane, packed-fp16 math, staggered 2x-unrolled pipeline (csr 1 iter
// ahead, data 2 iters ahead), unclamped prefetch via 16-entry pad.
// OUT16: fp16 h out. score = 0.6*(dl+dr)+0.4*sum(att*|s|); defer-max thr 8.

template<int F, int AMODE, bool OUT16>
__global__ __launch_bounds__(256) void agg_kernel(
    const _Float16* __restrict__ xlh, const _Float16* __restrict__ xrh,
    const float* __restrict__ att,
    const float* __restrict__ dl, const float* __restrict__ dr,
    const int* __restrict__ rowstart, const int* __restrict__ csr_src,
    void* __restrict__ outv, int n, int E, int ntiles)
{
    constexpr int LPE = F / 8;            // lanes per node (8 feats/lane)
    constexpr int LSH = (F == 64) ? 6 : 5;
    constexpr int NPG = 64 / LPE;         // nodes per wave

    int wv0  = (blockIdx.x * blockDim.x + threadIdx.x) >> 6;
    int nwaves = gridDim.x * (blockDim.x >> 6);
    int lane = threadIdx.x & 63;
    int grp = lane / LPE;
    int fl  = lane % LPE;

    h2 atth[4];
#pragma unroll
    for (int j = 0; j < 4; ++j) {
        atth[j][0] = (_Float16)att[fl * 8 + 2 * j];
        atth[j][1] = (_Float16)att[fl * 8 + 2 * j + 1];
    }

    for (int tile = wv0; tile < ntiles; tile += nwaves) {
        int node = tile * NPG + grp;
        bool act = node < n;
        int nc = act ? node : 0;

        float4 xrraw = *(const float4*)(xrh + (((unsigned)nc << LSH) + fl * 8));
        h2 xrv[4];
#pragma unroll
        for (int j = 0; j < 4; ++j) xrv[j] = u2h(((const unsigned*)&xrraw)[j]);
        float cdr = 0.6f * dr[nc];

        int s0 = rowstart[nc];
        int s1 = act ? rowstart[nc + 1] : s0;

        float m = -1e30f, mth = -1e30f, ssum = 0.f;
        float o[8];
#pragma unroll
        for (int j = 0; j < 8; ++j) o[j] = 0.f;

        // prologue (unclamped: pad covers overruns)
        int cA0 = csr_src[s0];
        int cB0 = csr_src[s0 + 1];
        int cA1 = csr_src[s0 + 2];
        int cB1 = csr_src[s0 + 3];
        float4 rA0 = *(const float4*)(xlh + (((unsigned)cA0 << LSH) + fl * 8));
        float4 rB0 = *(const float4*)(xlh + (((unsigned)cB0 << LSH) + fl * 8));
        float  dA0 = dl[cA0], dB0 = dl[cB0];
        float4 rA1 = *(const float4*)(xlh + (((unsigned)cA1 << LSH) + fl * 8));
        float4 rB1 = *(const float4*)(xlh + (((unsigned)cB1 << LSH) + fl * 8));
        float  dA1 = dl[cA1], dB1 = dl[cB1];
        int fA0 = csr_src[s0 + 4];
        int fB0 = csr_src[s0 + 5];
        int fA1 = csr_src[s0 + 6];
        int fB1 = csr_src[s0 + 7];

        int i0 = s0;

#define AGG_COMPUTE(RA, RB, DA, DB)                                          \
        {                                                                    \
            h2 a[4], b[4];                                                   \
            _Pragma("unroll")                                                \
            for (int j = 0; j < 4; ++j) {                                    \
                a[j] = u2h(((const unsigned*)&RA)[j]);                       \
                b[j] = u2h(((const unsigned*)&RB)[j]);                       \
            }                                                                \
            bool vb = (i0 + 1) < s1;                                         \
            float ta = 0.f, tb = 0.f;                                        \
            _Pragma("unroll")                                                \
            for (int j = 0; j < 4; ++j) {                                    \
                h2 ea = a[j] + xrv[j];                                       \
                h2 eb = b[j] + xrv[j];                                       \
                ea = u2h(h2u(ea) & 0x7FFF7FFFu);                             \
                eb = u2h(h2u(eb) & 0x7FFF7FFFu);                             \
                ta = dot2acc(atth[j], ea, ta);                               \
                tb = dot2acc(atth[j], eb, tb);                               \
            }                                                                \
            SWZ_ADD(ta, 0x041F); SWZ_ADD(tb, 0x041F);                        \
            SWZ_ADD(ta, 0x081F); SWZ_ADD(tb, 0x081F);                        \
            if (LPE == 8) { SWZ_ADD(ta, 0x101F); SWZ_ADD(tb, 0x101F); }      \
            float pa = 0.6f * DA + cdr + 0.4f * ta;                          \
            float pb = vb ? (0.6f * DB + cdr + 0.4f * tb) : -1e30f;          \
            float pm = fmaxf(pa, pb);                                        \
            if (pm > mth) {                                                  \
                float c = __expf(m - pm);                                    \
                ssum *= c;                                                   \
                _Pragma("unroll")                                            \
                for (int j = 0; j < 8; ++j) o[j] *= c;                       \
                m = pm; mth = pm + 8.0f;                                     \
            }                                                                \
            float wa = __expf(pa - m);                                       \
            float wb = __expf(pb - m);                                       \
            ssum += wa + wb;                                                 \
            _Pragma("unroll")                                                \
            for (int j = 0; j < 4; ++j) {                                    \
                o[2 * j]     += wa * (float)a[j][0] + wb * (float)b[j][0];   \
                o[2 * j + 1] += wa * (float)a[j][1] + wb * (float)b[j][1];   \
            }                                                                \
        }

        while (i0 < s1) {
            {
                int cA2 = fA0, cB2 = fB0;
                fA0 = csr_src[i0 + 8];
                fB0 = csr_src[i0 + 9];
                AGG_COMPUTE(rA0, rB0, dA0, dB0);
                rA0 = *(const float4*)(xlh + (((unsigned)cA2 << LSH) + fl * 8));
                rB0 = *(const float4*)(xlh + (((unsigned)cB2 << LSH) + fl * 8));
                dA0 = dl[cA2]; dB0 = dl[cB2];
            }
            i0 += 2;
            if (i0 >= s1) break;
            {
                int cA2 = fA1, cB2 = fB1;
                fA1 = csr_src[i0 + 8];
                fB1 = csr_src[i0 + 9];
                AGG_COMPUTE(rA1, rB1, dA1, dB1);
                rA1 = *(const float4*)(xlh + (((unsigned)cA2 << LSH) + fl * 8));
                rB1 = *(const float4*)(xlh + (((unsigned)cB2 << LSH) + fl * 8));
                dA1 = dl[cA2]; dB1 = dl[cB2];
            }
            i0 += 2;
        }
#undef AGG_COMPUTE

        float inv = 1.f / (ssum + 1e-16f);
        float res[8];
#pragma unroll
        for (int j = 0; j < 8; ++j) {
            float r = o[j] * inv;
            if (AMODE == 1) r = (r > 0.f) ? r : expm1f(r);
            else            r = (r > 0.f) ? r : 32.f * expm1f(r);
            res[j] = r;
        }
        if (act) {
            if (OUT16) {
                unsigned pk[4];
#pragma unroll
                for (int j = 0; j < 4; ++j) {
                    h2 t;
                    t[0] = (_Float16)res[2 * j];
                    t[1] = (_Float16)res[2 * j + 1];
                    pk[j] = h2u(t);
                }
                _Float16* op = (_Float16*)outv + (((unsigned)node << LSH) + fl * 8);
                *(float4*)op = *(const float4*)pk;
            } else {
                float* op = (float*)outv + (((unsigned)node << LSH) + fl * 8);
                *(float4*)op       = (float4){res[0], res[1], res[2], res[3]};
                *(float4*)(op + 4) = (float4){res[4], res[5], res[6], res[7]};
            }
        }
    }
}

// ================= launcher =================

extern "C" void kernel_launch(void* const* d_in, const int* in_sizes, int n_in,
                              void* d_out, int out_size, void* d_ws, size_t ws_size,
                              hipStream_t stream) {
    const float* x    = (const float*)d_in[0];
    const int*   ei   = (const int*)d_in[1];
    const float* Wl1  = (const float*)d_in[2];
    const float* Wr1  = (const float*)d_in[3];
    const float* att1 = (const float*)d_in[4];
    const float* Wl2  = (const float*)d_in[5];
    const float* Wr2  = (const float*)d_in[6];
    const float* att2 = (const float*)d_in[7];
    const float* Wl3  = (const float*)d_in[8];
    const float* Wr3  = (const float*)d_in[9];
    const float* att3 = (const float*)d_in[10];
    const float* Wl4  = (const float*)d_in[11];
    const float* Wr4  = (const float*)d_in[12];
    const float* att4 = (const float*)d_in[13];

    const int N = in_sizes[0] / 128;
    const int E = in_sizes[1] / 2;
    const int* src = ei;
    const int* dst = ei + E;

    const int nb  = (N + 127) >> BSHIFT;
    const int nbp = (nb + 15) & ~15;
    const int kgrid = (E + CH - 1) / CH;

    char* w = (char*)d_ws;
    size_t off = 0;
    auto take = [&](size_t bytes) -> void* {
        void* p = w + off;
        off = (off + bytes + 255) & ~(size_t)255;
        return p;
    };
    int* bh       = (int*)take((size_t)kgrid * nbp * 4);
    int* bbase    = (int*)take((size_t)(nb + 1) * 4);
    int* rowstart = (int*)take((size_t)(N + 1) * 4);
    int* csr_src  = (int*)take((size_t)(E + 16) * 4);   // +16 pad sentinels
    float* dl = (float*)take((size_t)N * 4);
    float* dr = (float*)take((size_t)N * 4);
    _Float16* xlh = (_Float16*)take((size_t)N * 64 * 2);
    _Float16* xrh = (_Float16*)take((size_t)N * 64 * 2);
    _Float16* hA  = (_Float16*)take((size_t)N * 64 * 2);
    _Float16* hB  = (_Float16*)take((size_t)N * 64 * 2);
    unsigned short* pWl1 = (unsigned short*)take(2 * 4 * 4 * 512 * 2);
    unsigned short* pWr1 = (unsigned short*)take(2 * 4 * 4 * 512 * 2);
    unsigned short* pWl2 = (unsigned short*)take(2 * 4 * 2 * 512 * 2);
    unsigned short* pWr2 = (unsigned short*)take(2 * 4 * 2 * 512 * 2);
    unsigned short* pWl3 = (unsigned short*)take(2 * 4 * 2 * 512 * 2);
    unsigned short* pWr3 = (unsigned short*)take(2 * 4 * 2 * 512 * 2);
    unsigned short* pWl4 = (unsigned short*)take(2 * 2 * 2 * 512 * 2);
    unsigned short* pWr4 = (unsigned short*)take(2 * 2 * 2 * 512 * 2);
    // pairs (E*4B = 6.4MB) aliases hA (12.8MB): consumed by bucket_finalize
    // before layer-1 agg writes hA (stream-ordered).
    unsigned* pairs = (unsigned*)hA;
    float* outf = (float*)d_out;

    hipMemsetAsync(csr_src + E, 0, 16 * 4, stream);   // pad -> node 0 (valid row)

    prepack_all<<<144, 256, 0, stream>>>(Wl1, Wr1, Wl2, Wr2, Wl3, Wr3, Wl4, Wr4,
                                         pWl1, pWr1, pWl2, pWr2, pWl3, pWr3, pWl4, pWr4);

    bucket_hist<<<kgrid, 256, 0, stream>>>(dst, bh, E, nb, nbp);
    bucket_scan<<<1, 1024, 0, stream>>>(bh, bbase, rowstart, nb, nbp, kgrid, E, N);
    bucket_scatter<<<kgrid, 256, 0, stream>>>(src, dst, bh, pairs, E, nb, nbp);
    bucket_finalize<<<nb, 256, 0, stream>>>(pairs, bbase, rowstart, csr_src, N);

    int pblk = (N + 63) / 64;
    const int AGGB = 2048;            // 8 blocks/CU * 4 waves = 32 waves/CU (HW cap)
    int nt64 = (N + 7) / 8;           // NPG=8 tiles
    int nt32 = (N + 15) / 16;         // NPG=16 tiles

    // layer 1: 128 -> 64, ELU (fp16 h out)
    proj_mfma_kernel<128, 64, false><<<pblk, 256, 0, stream>>>(x, pWl1, pWr1, att1, xlh, xrh, dl, dr, N);
    agg_kernel<64, 1, true><<<AGGB, 256, 0, stream>>>(xlh, xrh, att1, dl, dr, rowstart, csr_src, hA, N, E, nt64);

    // layer 2: 64 -> 64, ELU
    proj_mfma_kernel<64, 64, true><<<pblk, 256, 0, stream>>>(hA, pWl2, pWr2, att2, xlh, xrh, dl, dr, N);
    agg_kernel<64, 1, true><<<AGGB, 256, 0, stream>>>(xlh, xrh, att2, dl, dr, rowstart, csr_src, hB, N, E, nt64);

    // layer 3: 64 -> 64, ELU
    proj_mfma_kernel<64, 64, true><<<pblk, 256, 0, stream>>>(hB, pWl3, pWr3, att3, xlh, xrh, dl, dr, N);
    agg_kernel<64, 1, true><<<AGGB, 256, 0, stream>>>(xlh, xrh, att3, dl, dr, rowstart, csr_src, hA, N, E, nt64);

    // layer 4: 64 -> 32, final ELU (alpha = 32), f32 out
    proj_mfma_kernel<64, 32, true><<<pblk, 256, 0, stream>>>(hA, pWl4, pWr4, att4, xlh, xrh, dl, dr, N);
    agg_kernel<32, 2, false><<<AGGB, 256, 0, stream>>>(xlh, xrh, att4, dl, dr, rowstart, csr_src, outf, N, E, nt32);
}

// Round 20
// 290.166 us; speedup vs baseline: 1.2305x; 1.2305x over previous
//
#include <hip/hip_runtime.h>
#include <math.h>

typedef __attribute__((ext_vector_type(8))) short bf16x8;
typedef __attribute__((ext_vector_type(4))) float f32x4;
typedef __attribute__((ext_vector_type(2))) _Float16 h2;

#define BSHIFT 7               // 128 nodes per bucket
#define CH 8192                // edges per block in bucket hist/scatter

__device__ inline unsigned short f32_to_bf16_bits(float f) {
    unsigned int u = __float_as_uint(f);
    unsigned int r = (u + 0x7fffu + ((u >> 16) & 1u)) >> 16;   // RNE
    return (unsigned short)r;
}
__device__ inline float bf16_bits_to_f32(unsigned short h) {
    return __uint_as_float(((unsigned int)h) << 16);
}
__device__ inline h2 u2h(unsigned u) { return __builtin_bit_cast(h2, u); }
__device__ inline unsigned h2u(h2 h) { return __builtin_bit_cast(unsigned, h); }

// single-instruction lane xor-swizzle add (BitMode: (xor<<10)|0x1F)
#define SWZ_ADD(t, imm) \
    t += __int_as_float(__builtin_amdgcn_ds_swizzle(__float_as_int(t), imm))

// fp16 pair dot with f32 accumulate (v_dot2_f32_f16)
__device__ inline float dot2acc(h2 a, h2 b, float c) {
#if defined(__has_builtin)
#if __has_builtin(__builtin_amdgcn_fdot2)
    return __builtin_amdgcn_fdot2(a, b, c, false);
#else
    return c + (float)a[0] * (float)b[0] + (float)a[1] * (float)b[1];
#endif
#else
    return c + (float)a[0] * (float)b[0] + (float)a[1] * (float)b[1];
#endif
}

// ================= exact per-block-count CSR build =================
// bh[block][bucket]: hist writes per-block LDS histograms (no global
// atomics); scanA (wave per bucket) makes exclusive per-(block,bucket)
// prefixes; scanB scans bucket totals; scatter adds bbase on cursor load.

__global__ __launch_bounds__(256) void bucket_hist(
    const int* __restrict__ dst, int* __restrict__ bh, int E, int nb, int nbp)
{
    __shared__ int h[1024];
    for (int i = threadIdx.x; i < nb; i += 256) h[i] = 0;
    __syncthreads();
    int e0 = blockIdx.x * CH, e1 = min(e0 + CH, E);
    for (int e = e0 + (int)threadIdx.x; e < e1; e += 256)
        atomicAdd(&h[dst[e] >> BSHIFT], 1);
    __syncthreads();
    for (int b = threadIdx.x; b < nb; b += 256)
        bh[(size_t)blockIdx.x * nbp + b] = h[b];
}

// one wave per bucket: exclusive prefix over the kgrid chunk entries.
__global__ __launch_bounds__(256) void bucket_scanA(
    int* __restrict__ bh, int* __restrict__ btot, int nb, int nbp, int kgrid)
{
    int wv = (blockIdx.x * 256 + threadIdx.x) >> 6;
    int lane = threadIdx.x & 63;
    if (wv >= nb) return;
    int run = 0;
    for (int b0 = 0; b0 < kgrid; b0 += 64) {
        int b = b0 + lane;
        int v = (b < kgrid) ? bh[(size_t)b * nbp + wv] : 0;
        int s = v;
#pragma unroll
        for (int off = 1; off < 64; off <<= 1) {
            int u = __shfl_up(s, off);
            if (lane >= off) s += u;
        }
        int excl = s - v + run;
        if (b < kgrid) bh[(size_t)b * nbp + wv] = excl;
        run += __shfl(s, 63);
    }
    if (lane == 0) btot[wv] = run;
}

// one block: scan bucket totals -> exclusive bases.
__global__ void bucket_scanB(const int* __restrict__ btot, int* __restrict__ bbase,
                             int* __restrict__ rowstart, int nb, int E, int N)
{
    __shared__ int sh[1024];
    int t = threadIdx.x;
    int v = (t < nb) ? btot[t] : 0;
    sh[t] = v;
    __syncthreads();
    for (int d = 1; d < 1024; d <<= 1) {
        int a = (t >= d) ? sh[t - d] : 0;
        __syncthreads();
        sh[t] += a;
        __syncthreads();
    }
    if (t < nb) bbase[t] = sh[t] - v;
    if (t == nb) bbase[t] = E;
    if (t == 0) rowstart[N] = E;
}

__global__ __launch_bounds__(256) void bucket_scatter(
    const int* __restrict__ src, const int* __restrict__ dst,
    const int* __restrict__ bh, const int* __restrict__ bbase,
    unsigned* __restrict__ pairs, int E, int nb, int nbp)
{
    __shared__ int cur[1024];
    for (int i = threadIdx.x; i < nb; i += 256)
        cur[i] = bh[(size_t)blockIdx.x * nbp + i] + bbase[i];
    __syncthreads();
    int e0 = blockIdx.x * CH, e1 = min(e0 + CH, E);
    for (int e = e0 + (int)threadIdx.x; e < e1; e += 256) {
        int d = dst[e];
        int pos = atomicAdd(&cur[d >> BSHIFT], 1);
        pairs[pos] = ((unsigned)src[e] << BSHIFT) | (unsigned)(d & 127);
    }
}

// one block per bucket: local hist + scan -> rowstart, then local scatter.
__global__ __launch_bounds__(256) void bucket_finalize(
    const unsigned* __restrict__ pairs, const int* __restrict__ bbase,
    int* __restrict__ rowstart, int* __restrict__ csr_src, int N)
{
    __shared__ int h[128];
    __shared__ int sh[256];
    int b = blockIdx.x;
    int p0 = bbase[b], p1 = bbase[b + 1];
    int t = threadIdx.x;
    if (t < 128) h[t] = 0;
    __syncthreads();
    for (int e = p0 + t; e < p1; e += 256)
        atomicAdd(&h[pairs[e] & 127], 1);
    __syncthreads();
    int v = (t < 128) ? h[t] : 0;
    sh[t] = v;
    __syncthreads();
    for (int d = 1; d < 256; d <<= 1) {
        int a = (t >= d) ? sh[t - d] : 0;
        __syncthreads();
        sh[t] += a;
        __syncthreads();
    }
    if (t < 128) {
        int off = sh[t] - v;
        int node = (b << BSHIFT) + t;
        if (node < N) rowstart[node] = p0 + off;
        h[t] = p0 + off;
    }
    __syncthreads();
    for (int e = p0 + t; e < p1; e += 256) {
        unsigned pr = pairs[e];
        int pos = atomicAdd(&h[pr & 127], 1);
        csr_src[pos] = (int)(pr >> BSHIFT);
    }
}

// ================= weight prepack (all layers, one launch) =================

__device__ inline void prepack_one(const float* __restrict__ W, unsigned short* __restrict__ P,
                                   int FIN, int FOUT, int ii) {
    int NT = FOUT >> 4, NK = FIN >> 5;
    int part = NT * NK * 512;
    int j = ii & 7;
    int lane = (ii >> 3) & 63;
    int rest = ii >> 9;
    int ks = rest % NK;
    int t = rest / NK;
    int k = ks * 32 + (lane >> 4) * 8 + j;
    int c = t * 16 + (lane & 15);
    float w = W[(size_t)k * FOUT + c];
    unsigned short hi = f32_to_bf16_bits(w);
    unsigned short lo = f32_to_bf16_bits(w - bf16_bits_to_f32(hi));
    P[ii] = hi;
    P[part + ii] = lo;
}

__global__ void prepack_all(
    const float* Wl1, const float* Wr1, const float* Wl2, const float* Wr2,
    const float* Wl3, const float* Wr3, const float* Wl4, const float* Wr4,
    unsigned short* pWl1, unsigned short* pWr1, unsigned short* pWl2, unsigned short* pWr2,
    unsigned short* pWl3, unsigned short* pWr3, unsigned short* pWl4, unsigned short* pWr4)
{
    int i = blockIdx.x * 256 + threadIdx.x;
    if      (i < 8192)  prepack_one(Wl1, pWl1, 128, 64, i);
    else if (i < 16384) prepack_one(Wr1, pWr1, 128, 64, i - 8192);
    else if (i < 20480) prepack_one(Wl2, pWl2, 64, 64, i - 16384);
    else if (i < 24576) prepack_one(Wr2, pWr2, 64, 64, i - 20480);
    else if (i < 28672) prepack_one(Wl3, pWl3, 64, 64, i - 24576);
    else if (i < 32768) prepack_one(Wr3, pWr3, 64, 64, i - 28672);
    else if (i < 34816) prepack_one(Wl4, pWl4, 64, 32, i - 32768);
    else if (i < 36864) prepack_one(Wr4, pWr4, 64, 32, i - 34816);
}

// ================= MFMA projection + att-dot epilogue =================
// IN16: input h stored fp16 (layers 2-4); fp16 = bf16hi + bf16lo exactly.

template<int FIN, int FOUT, bool IN16>
__global__ __launch_bounds__(256) void proj_mfma_kernel(
    const void* __restrict__ xin,
    const unsigned short* __restrict__ pWl, const unsigned short* __restrict__ pWr,
    const float* __restrict__ att,
    _Float16* __restrict__ xlh, _Float16* __restrict__ xrh,
    float* __restrict__ dl, float* __restrict__ dr, int n)
{
    constexpr int NT = FOUT >> 4;
    constexpr int NK = FIN >> 5;
    constexpr int PART = NT * NK * 512;
    const int wave = threadIdx.x >> 6;
    const int lane = threadIdx.x & 63;
    const int row0 = blockIdx.x * 64 + wave * 16;
    int arow = row0 + (lane & 15);
    if (arow >= n) arow = n - 1;
    const int khalf = lane >> 4;

    f32x4 accl[NT], accr[NT];
#pragma unroll
    for (int t = 0; t < NT; ++t) {
        accl[t] = (f32x4){0.f, 0.f, 0.f, 0.f};
        accr[t] = (f32x4){0.f, 0.f, 0.f, 0.f};
    }

#pragma unroll
    for (int ks = 0; ks < NK; ++ks) {
        float av[8];
        if (IN16) {
            const _Float16* xrow = (const _Float16*)xin + (size_t)arow * FIN + khalf * 8;
            float4 raw = *(const float4*)(xrow + ks * 32);
            const unsigned* u = (const unsigned*)&raw;
#pragma unroll
            for (int j = 0; j < 4; ++j) {
                h2 p = u2h(u[j]);
                av[2 * j]     = (float)p[0];
                av[2 * j + 1] = (float)p[1];
            }
        } else {
            const float* xrow = (const float*)xin + (size_t)arow * FIN + khalf * 8;
            float4 a0 = *(const float4*)(xrow + ks * 32);
            float4 a1 = *(const float4*)(xrow + ks * 32 + 4);
            av[0] = a0.x; av[1] = a0.y; av[2] = a0.z; av[3] = a0.w;
            av[4] = a1.x; av[5] = a1.y; av[6] = a1.z; av[7] = a1.w;
        }
        bf16x8 ah, al;
#pragma unroll
        for (int j = 0; j < 8; ++j) {
            unsigned short h = f32_to_bf16_bits(av[j]);
            ah[j] = (short)h;
            al[j] = (short)f32_to_bf16_bits(av[j] - bf16_bits_to_f32(h));
        }
#pragma unroll
        for (int t = 0; t < NT; ++t) {
            const unsigned short* bpl = pWl + ((size_t)(t * NK + ks) * 64 + lane) * 8;
            bf16x8 bh  = *(const bf16x8*)bpl;
            bf16x8 blo = *(const bf16x8*)(bpl + PART);
            accl[t] = __builtin_amdgcn_mfma_f32_16x16x32_bf16(ah, bh,  accl[t], 0, 0, 0);
            accl[t] = __builtin_amdgcn_mfma_f32_16x16x32_bf16(ah, blo, accl[t], 0, 0, 0);
            accl[t] = __builtin_amdgcn_mfma_f32_16x16x32_bf16(al, bh,  accl[t], 0, 0, 0);
            const unsigned short* bpr = pWr + ((size_t)(t * NK + ks) * 64 + lane) * 8;
            bh  = *(const bf16x8*)bpr;
            blo = *(const bf16x8*)(bpr + PART);
            accr[t] = __builtin_amdgcn_mfma_f32_16x16x32_bf16(ah, bh,  accr[t], 0, 0, 0);
            accr[t] = __builtin_amdgcn_mfma_f32_16x16x32_bf16(ah, blo, accr[t], 0, 0, 0);
            accr[t] = __builtin_amdgcn_mfma_f32_16x16x32_bf16(al, bh,  accr[t], 0, 0, 0);
        }
    }

    const int orow0 = row0 + khalf * 4;
    const int colb = lane & 15;
    float attc[NT];
#pragma unroll
    for (int t = 0; t < NT; ++t) attc[t] = att[t * 16 + colb];

#pragma unroll
    for (int t = 0; t < NT; ++t) {
        int col = t * 16 + colb;
#pragma unroll
        for (int r = 0; r < 4; ++r) {
            int rr = orow0 + r;
            if (rr < n) {
                xlh[(size_t)rr * FOUT + col] = (_Float16)accl[t][r];
                xrh[(size_t)rr * FOUT + col] = (_Float16)accr[t][r];
            }
        }
    }
#pragma unroll
    for (int r = 0; r < 4; ++r) {
        float pl = 0.f, pr = 0.f;
#pragma unroll
        for (int t = 0; t < NT; ++t) { pl += accl[t][r] * attc[t]; pr += accr[t][r] * attc[t]; }
#pragma unroll
        for (int off = 1; off < 16; off <<= 1) {
            pl += __shfl_xor(pl, off);
            pr += __shfl_xor(pr, off);
        }
        int rr = orow0 + r;
        if (colb == 0 && rr < n) { dl[rr] = pl; dr[rr] = pr; }
    }
}

// ================= per-dst online-softmax aggregation =================
// Static persistent grid-stride (2048 blocks = 32 waves/CU); group-per-node,
// 8 feats/lane, packed-fp16 math, staggered 2x-unrolled pipeline (csr 1 iter
// ahead, data 2 iters ahead), unclamped prefetch via 16-entry pad.
// OUT16: fp16 h out. score = 0.6*(dl+dr)+0.4*sum(att*|s|); defer-max thr 8.

template<int F, int AMODE, bool OUT16>
__global__ __launch_bounds__(256) void agg_kernel(
    const _Float16* __restrict__ xlh, const _Float16* __restrict__ xrh,
    const float* __restrict__ att,
    const float* __restrict__ dl, const float* __restrict__ dr,
    const int* __restrict__ rowstart, const int* __restrict__ csr_src,
    void* __restrict__ outv, int n, int E, int ntiles)
{
    constexpr int LPE = F / 8;            // lanes per node (8 feats/lane)
    constexpr int LSH = (F == 64) ? 6 : 5;
    constexpr int NPG = 64 / LPE;         // nodes per wave

    int wv0  = (blockIdx.x * blockDim.x + threadIdx.x) >> 6;
    int nwaves = gridDim.x * (blockDim.x >> 6);
    int lane = threadIdx.x & 63;
    int grp = lane / LPE;
    int fl  = lane % LPE;

    h2 atth[4];
#pragma unroll
    for (int j = 0; j < 4; ++j) {
        atth[j][0] = (_Float16)att[fl * 8 + 2 * j];
        atth[j][1] = (_Float16)att[fl * 8 + 2 * j + 1];
    }

    for (int tile = wv0; tile < ntiles; tile += nwaves) {
        int node = tile * NPG + grp;
        bool act = node < n;
        int nc = act ? node : 0;

        float4 xrraw = *(const float4*)(xrh + (((unsigned)nc << LSH) + fl * 8));
        h2 xrv[4];
#pragma unroll
        for (int j = 0; j < 4; ++j) xrv[j] = u2h(((const unsigned*)&xrraw)[j]);
        float cdr = 0.6f * dr[nc];

        int s0 = rowstart[nc];
        int s1 = act ? rowstart[nc + 1] : s0;

        float m = -1e30f, mth = -1e30f, ssum = 0.f;
        float o[8];
#pragma unroll
        for (int j = 0; j < 8; ++j) o[j] = 0.f;

        // prologue (unclamped: pad covers overruns)
        int cA0 = csr_src[s0];
        int cB0 = csr_src[s0 + 1];
        int cA1 = csr_src[s0 + 2];
        int cB1 = csr_src[s0 + 3];
        float4 rA0 = *(const float4*)(xlh + (((unsigned)cA0 << LSH) + fl * 8));
        float4 rB0 = *(const float4*)(xlh + (((unsigned)cB0 << LSH) + fl * 8));
        float  dA0 = dl[cA0], dB0 = dl[cB0];
        float4 rA1 = *(const float4*)(xlh + (((unsigned)cA1 << LSH) + fl * 8));
        float4 rB1 = *(const float4*)(xlh + (((unsigned)cB1 << LSH) + fl * 8));
        float  dA1 = dl[cA1], dB1 = dl[cB1];
        int fA0 = csr_src[s0 + 4];
        int fB0 = csr_src[s0 + 5];
        int fA1 = csr_src[s0 + 6];
        int fB1 = csr_src[s0 + 7];

        int i0 = s0;

#define AGG_COMPUTE(RA, RB, DA, DB)                                          \
        {                                                                    \
            h2 a[4], b[4];                                                   \
            _Pragma("unroll")                                                \
            for (int j = 0; j < 4; ++j) {                                    \
                a[j] = u2h(((const unsigned*)&RA)[j]);                       \
                b[j] = u2h(((const unsigned*)&RB)[j]);                       \
            }                                                                \
            bool vb = (i0 + 1) < s1;                                         \
            float ta = 0.f, tb = 0.f;                                        \
            _Pragma("unroll")                                                \
            for (int j = 0; j < 4; ++j) {                                    \
                h2 ea = a[j] + xrv[j];                                       \
                h2 eb = b[j] + xrv[j];                                       \
                ea = u2h(h2u(ea) & 0x7FFF7FFFu);                             \
                eb = u2h(h2u(eb) & 0x7FFF7FFFu);                             \
                ta = dot2acc(atth[j], ea, ta);                               \
                tb = dot2acc(atth[j], eb, tb);                               \
            }                                                                \
            SWZ_ADD(ta, 0x041F); SWZ_ADD(tb, 0x041F);                        \
            SWZ_ADD(ta, 0x081F); SWZ_ADD(tb, 0x081F);                        \
            if (LPE == 8) { SWZ_ADD(ta, 0x101F); SWZ_ADD(tb, 0x101F); }      \
            float pa = 0.6f * DA + cdr + 0.4f * ta;                          \
            float pb = vb ? (0.6f * DB + cdr + 0.4f * tb) : -1e30f;          \
            float pm = fmaxf(pa, pb);                                        \
            if (pm > mth) {                                                  \
                float c = __expf(m - pm);                                    \
                ssum *= c;                                                   \
                _Pragma("unroll")                                            \
                for (int j = 0; j < 8; ++j) o[j] *= c;                       \
                m = pm; mth = pm + 8.0f;                                     \
            }                                                                \
            float wa = __expf(pa - m);                                       \
            float wb = __expf(pb - m);                                       \
            ssum += wa + wb;                                                 \
            _Pragma("unroll")                                                \
            for (int j = 0; j < 4; ++j) {                                    \
                o[2 * j]     += wa * (float)a[j][0] + wb * (float)b[j][0];   \
                o[2 * j + 1] += wa * (float)a[j][1] + wb * (float)b[j][1];   \
            }                                                                \
        }

        while (i0 < s1) {
            {
                int cA2 = fA0, cB2 = fB0;
                fA0 = csr_src[i0 + 8];
                fB0 = csr_src[i0 + 9];
                AGG_COMPUTE(rA0, rB0, dA0, dB0);
                rA0 = *(const float4*)(xlh + (((unsigned)cA2 << LSH) + fl * 8));
                rB0 = *(const float4*)(xlh + (((unsigned)cB2 << LSH) + fl * 8));
                dA0 = dl[cA2]; dB0 = dl[cB2];
            }
            i0 += 2;
            if (i0 >= s1) break;
            {
                int cA2 = fA1, cB2 = fB1;
                fA1 = csr_src[i0 + 8];
                fB1 = csr_src[i0 + 9];
                AGG_COMPUTE(rA1, rB1, dA1, dB1);
                rA1 = *(const float4*)(xlh + (((unsigned)cA2 << LSH) + fl * 8));
                rB1 = *(const float4*)(xlh + (((unsigned)cB2 << LSH) + fl * 8));
                dA1 = dl[cA2]; dB1 = dl[cB2];
            }
            i0 += 2;
        }
#undef AGG_COMPUTE

        float inv = 1.f / (ssum + 1e-16f);
        float res[8];
#pragma unroll
        for (int j = 0; j < 8; ++j) {
            float r = o[j] * inv;
            if (AMODE == 1) r = (r > 0.f) ? r : expm1f(r);
            else            r = (r > 0.f) ? r : 32.f * expm1f(r);
            res[j] = r;
        }
        if (act) {
            if (OUT16) {
                unsigned pk[4];
#pragma unroll
                for (int j = 0; j < 4; ++j) {
                    h2 t;
                    t[0] = (_Float16)res[2 * j];
                    t[1] = (_Float16)res[2 * j + 1];
                    pk[j] = h2u(t);
                }
                _Float16* op = (_Float16*)outv + (((unsigned)node << LSH) + fl * 8);
                *(float4*)op = *(const float4*)pk;
            } else {
                float* op = (float*)outv + (((unsigned)node << LSH) + fl * 8);
                *(float4*)op       = (float4){res[0], res[1], res[2], res[3]};
                *(float4*)(op + 4) = (float4){res[4], res[5], res[6], res[7]};
            }
        }
    }
}

// ================= launcher =================

extern "C" void kernel_launch(void* const* d_in, const int* in_sizes, int n_in,
                              void* d_out, int out_size, void* d_ws, size_t ws_size,
                              hipStream_t stream) {
    const float* x    = (const float*)d_in[0];
    const int*   ei   = (const int*)d_in[1];
    const float* Wl1  = (const float*)d_in[2];
    const float* Wr1  = (const float*)d_in[3];
    const float* att1 = (const float*)d_in[4];
    const float* Wl2  = (const float*)d_in[5];
    const float* Wr2  = (const float*)d_in[6];
    const float* att2 = (const float*)d_in[7];
    const float* Wl3  = (const float*)d_in[8];
    const float* Wr3  = (const float*)d_in[9];
    const float* att3 = (const float*)d_in[10];
    const float* Wl4  = (const float*)d_in[11];
    const float* Wr4  = (const float*)d_in[12];
    const float* att4 = (const float*)d_in[13];

    const int N = in_sizes[0] / 128;
    const int E = in_sizes[1] / 2;
    const int* src = ei;
    const int* dst = ei + E;

    const int nb  = (N + 127) >> BSHIFT;
    const int nbp = (nb + 15) & ~15;
    const int kgrid = (E + CH - 1) / CH;

    char* w = (char*)d_ws;
    size_t off = 0;
    auto take = [&](size_t bytes) -> void* {
        void* p = w + off;
        off = (off + bytes + 255) & ~(size_t)255;
        return p;
    };
    int* bh       = (int*)take((size_t)kgrid * nbp * 4);
    int* btot     = (int*)take((size_t)nbp * 4);
    int* bbase    = (int*)take((size_t)(nb + 1) * 4);
    int* rowstart = (int*)take((size_t)(N + 1) * 4);
    int* csr_src  = (int*)take((size_t)(E + 16) * 4);   // +16 pad sentinels
    float* dl = (float*)take((size_t)N * 4);
    float* dr = (float*)take((size_t)N * 4);
    _Float16* xlh = (_Float16*)take((size_t)N * 64 * 2);
    _Float16* xrh = (_Float16*)take((size_t)N * 64 * 2);
    _Float16* hA  = (_Float16*)take((size_t)N * 64 * 2);
    _Float16* hB  = (_Float16*)take((size_t)N * 64 * 2);
    unsigned short* pWl1 = (unsigned short*)take(2 * 4 * 4 * 512 * 2);
    unsigned short* pWr1 = (unsigned short*)take(2 * 4 * 4 * 512 * 2);
    unsigned short* pWl2 = (unsigned short*)take(2 * 4 * 2 * 512 * 2);
    unsigned short* pWr2 = (unsigned short*)take(2 * 4 * 2 * 512 * 2);
    unsigned short* pWl3 = (unsigned short*)take(2 * 4 * 2 * 512 * 2);
    unsigned short* pWr3 = (unsigned short*)take(2 * 4 * 2 * 512 * 2);
    unsigned short* pWl4 = (unsigned short*)take(2 * 2 * 2 * 512 * 2);
    unsigned short* pWr4 = (unsigned short*)take(2 * 2 * 2 * 512 * 2);
    // pairs (E*4B = 6.4MB) aliases hA (12.8MB): consumed by bucket_finalize
    // before layer-1 agg writes hA (stream-ordered).
    unsigned* pairs = (unsigned*)hA;
    float* outf = (float*)d_out;

    hipMemsetAsync(csr_src + E, 0, 16 * 4, stream);   // pad -> node 0 (valid row)

    prepack_all<<<144, 256, 0, stream>>>(Wl1, Wr1, Wl2, Wr2, Wl3, Wr3, Wl4, Wr4,
                                         pWl1, pWr1, pWl2, pWr2, pWl3, pWr3, pWl4, pWr4);

    bucket_hist<<<kgrid, 256, 0, stream>>>(dst, bh, E, nb, nbp);
    bucket_scanA<<<(nb + 3) / 4, 256, 0, stream>>>(bh, btot, nb, nbp, kgrid);
    bucket_scanB<<<1, 1024, 0, stream>>>(btot, bbase, rowstart, nb, E, N);
    bucket_scatter<<<kgrid, 256, 0, stream>>>(src, dst, bh, bbase, pairs, E, nb, nbp);
    bucket_finalize<<<nb, 256, 0, stream>>>(pairs, bbase, rowstart, csr_src, N);

    int pblk = (N + 63) / 64;
    const int AGGB = 2048;            // 8 blocks/CU * 4 waves = 32 waves/CU (HW cap)
    int nt64 = (N + 7) / 8;           // NPG=8 tiles
    int nt32 = (N + 15) / 16;         // NPG=16 tiles

    // layer 1: 128 -> 64, ELU (fp16 h out)
    proj_mfma_kernel<128, 64, false><<<pblk, 256, 0, stream>>>(x, pWl1, pWr1, att1, xlh, xrh, dl, dr, N);
    agg_kernel<64, 1, true><<<AGGB, 256, 0, stream>>>(xlh, xrh, att1, dl, dr, rowstart, csr_src, hA, N, E, nt64);

    // layer 2: 64 -> 64, ELU
    proj_mfma_kernel<64, 64, true><<<pblk, 256, 0, stream>>>(hA, pWl2, pWr2, att2, xlh, xrh, dl, dr, N);
    agg_kernel<64, 1, true><<<AGGB, 256, 0, stream>>>(xlh, xrh, att2, dl, dr, rowstart, csr_src, hB, N, E, nt64);

    // layer 3: 64 -> 64, ELU
    proj_mfma_kernel<64, 64, true><<<pblk, 256, 0, stream>>>(hB, pWl3, pWr3, att3, xlh, xrh, dl, dr, N);
    agg_kernel<64, 1, true><<<AGGB, 256, 0, stream>>>(xlh, xrh, att3, dl, dr, rowstart, csr_src, hA, N, E, nt64);

    // layer 4: 64 -> 32, final ELU (alpha = 32), f32 out
    proj_mfma_kernel<64, 32, true><<<pblk, 256, 0, stream>>>(hA, pWl4, pWr4, att4, xlh, xrh, dl, dr, N);
    agg_kernel<32, 2, false><<<AGGB, 256, 0, stream>>>(xlh, xrh, att4, dl, dr, rowstart, csr_src, outf, N, E, nt32);
}